// Round 3
// baseline (375.586 us; speedup 1.0000x reference)
//
#include <hip/hip_runtime.h>
#include <math.h>

#define DIM 512
#define KCB 1024
#define BM  64
// ws layout (bytes)
#define CBT_OFF   0u         // CB fp16 pre-swizzled: [2 halves][16 chunks of 32 d][32KB] = 1 MB
#define CNORM_OFF 1048576u   // 4 KB
#define XNORM_OFF 1052672u   // 256 KB
#define HIST_OFF  1314816u   // 4 KB
#define LOSS_OFF  1318912u   // 64 B
#define XO 16                // X fp16 region offset inside d_out (block-owned slabs)

typedef _Float16 half8 __attribute__((ext_vector_type(8)));
typedef float floatx4 __attribute__((ext_vector_type(4)));

// async global->LDS DMA, 16B/lane; LDS dest = wave-uniform base + lane*16
__device__ __forceinline__ void g2l16(const void* g, void* l) {
    __builtin_amdgcn_global_load_lds(
        (const __attribute__((address_space(1))) unsigned int*)g,
        (__attribute__((address_space(3))) unsigned int*)l, 16, 0, 0);
}

// asm ds_read_b128 with compile-time offset; data valid only after lgkmcnt wait
template<int OFF>
__device__ __forceinline__ half8 ldsr(unsigned addr) {
    half8 r;
    asm volatile("ds_read_b128 %0, %1 offset:%c2" : "=v"(r) : "v"(addr), "n"(OFF));
    return r;
}

__device__ __forceinline__ half8 cvt8(float4 a, float4 b) {
    half8 h;
    h[0] = (_Float16)a.x; h[1] = (_Float16)a.y; h[2] = (_Float16)a.z; h[3] = (_Float16)a.w;
    h[4] = (_Float16)b.x; h[5] = (_Float16)b.y; h[6] = (_Float16)b.z; h[7] = (_Float16)b.w;
    return h;
}
__device__ __forceinline__ float sq8(float4 a, float4 b) {
    return a.x*a.x + a.y*a.y + a.z*a.z + a.w*a.w
         + b.x*b.x + b.y*b.y + b.z*b.z + b.w*b.w;
}

// 32-d chunk image layout: granule = 8 halves (16B) of (row r, q-group q in 0..3).
// line = r>>1 (128B line = 2 rows), slot = ((r&1)*4 + q) ^ (line&7).
// Linear slot order = DMA-compatible (rule #21, pre-swizzled source).

// ---------------- merged prep: X->fp16 swizzled + xnorm | CB->fp16 swizzled + cnorm ----------------
__global__ __launch_bounds__(256) void prep(const float* __restrict__ X,
                                            const float* __restrict__ CB,
                                            char* __restrict__ ob,
                                            char* __restrict__ ws) {
    const int t = threadIdx.x;
    const int w = t >> 6, lane = t & 63;
    const int dc = lane >> 2, q = lane & 3;  // lane covers d = lane*8..+7
    const int b = blockIdx.x;
    if (b < 2048) {
        for (int it = 0; it < 8; ++it) {
            int r = b * 32 + w * 8 + it;
            const float4* src = (const float4*)(X + (size_t)r * DIM);
            float4 v0 = src[lane * 2];
            float4 v1 = src[lane * 2 + 1];
            int rl = r & 63;
            int line = rl >> 1;
            int sl = ((((rl & 1) << 2) | q) ^ (line & 7));
            *(half8*)(ob + XO + (size_t)(r >> 6) * 131072 + dc * 4096
                      + (line * 8 + sl) * 16) = cvt8(v0, v1);
            float s = sq8(v0, v1);
#pragma unroll
            for (int off = 32; off > 0; off >>= 1) s += __shfl_xor(s, off);
            if (lane == 0) ((float*)(ws + XNORM_OFF))[r] = s;
        }
    } else {
        int k = (b - 2048) * 4 + w;  // one code per wave
        const float4* src = (const float4*)(CB + (size_t)k * DIM);
        float4 v0 = src[lane * 2];
        float4 v1 = src[lane * 2 + 1];
        int kl = k & 511;
        int line = kl >> 1;
        int sl = ((((kl & 1) << 2) | q) ^ (line & 7));
        *(half8*)(ws + CBT_OFF + (size_t)(k >> 9) * 524288 + dc * 32768
                  + (line * 8 + sl) * 16) = cvt8(v0, v1);
        float s = sq8(v0, v1);
#pragma unroll
        for (int off = 32; off > 0; off >>= 1) s += __shfl_xor(s, off);
        if (lane == 0) ((float*)(ws + CNORM_OFF))[k] = s;
    }
}

// ---------------- main: counted-vmcnt pipelined MFMA scores + fused argmin/epilogue ----------------
__global__ __launch_bounds__(256, 2) void vq_main(
    char* __restrict__ ob, const float* __restrict__ CB32,
    const char* __restrict__ ws, int* __restrict__ hist,
    float* __restrict__ loss_acc) {
    extern __shared__ char smem[];
    // cbuf0 @0 (32KB), cbuf1 @32768 (32KB), xbuf0 @65536 (4KB), xbuf1 @69632 (4KB) = 73728
    float* argS = (float*)smem;           // epilogue overlay [4][64]
    int*   argI = (int*)(smem + 1024);    // [4][64]
    int*   idxF = (int*)(smem + 2048);    // [64]

    const int t = threadIdx.x;
    const int lane = t & 63;
    const int wu = __builtin_amdgcn_readfirstlane(t >> 6);  // wave id (scalar)
    const int ln = lane & 15, q = lane >> 4;
    const int rb = blockIdx.x;
    const int rowbase = rb * BM;
    const float* cnorm = (const float*)(ws + CNORM_OFF);
    const float* xnorm = (const float*)(ws + XNORM_OFF);

    // conflict-free swizzled read offset within a 1KB (16-row) sub-block
    const int xoff = (ln >> 1) * 128 + (((((ln & 1) << 2) | q) ^ (ln >> 1)) << 4);

    const char* cbase = ws + CBT_OFF;
    const char* xbase = ob + XO + (size_t)rb * 131072;
    const unsigned smemu = (unsigned)(uintptr_t)smem;  // LDS byte offset (aperture 4GB-aligned)

    // preload cnorm into regs (no vector loads left inside the loop)
    float cnr0[8], cnr1[8];
#pragma unroll
    for (int bc = 0; bc < 8; ++bc) {
        cnr0[bc] = cnorm[wu * 128 + bc * 16 + ln];
        cnr1[bc] = cnorm[512 + wu * 128 + bc * 16 + ln];
    }
    asm volatile("" : "+v"(cnr0[0]), "+v"(cnr0[1]), "+v"(cnr0[2]), "+v"(cnr0[3]),
                      "+v"(cnr0[4]), "+v"(cnr0[5]), "+v"(cnr0[6]), "+v"(cnr0[7]));
    asm volatile("" : "+v"(cnr1[0]), "+v"(cnr1[1]), "+v"(cnr1[2]), "+v"(cnr1[3]),
                      "+v"(cnr1[4]), "+v"(cnr1[5]), "+v"(cnr1[6]), "+v"(cnr1[7]));

    float bestS[16];
    int bestI[16];
#pragma unroll
    for (int li = 0; li < 16; ++li) { bestS[li] = 3.0e38f; bestI[li] = 0; }

    // ---- prologue bundle: X(0), CB(0) -> buffers 0 (9 DMAs/wave) ----
    g2l16(xbase + (wu * 64 + lane) * 16, smem + 65536 + wu * 1024);
#pragma unroll
    for (int i = 0; i < 8; ++i) {
        int p = i * 4 + wu;
        g2l16(cbase + p * 1024 + lane * 16, smem + p * 1024);
    }

    for (int h = 0; h < 2; ++h) {
        floatx4 acc[4][8];
#pragma unroll
        for (int ar = 0; ar < 4; ++ar)
#pragma unroll
            for (int bc = 0; bc < 8; ++bc) acc[ar][bc] = (floatx4){0.f, 0.f, 0.f, 0.f};

#pragma unroll 2
        for (int dc = 0; dc < 16; ++dc) {
            const int cb = dc & 1;          // compile-time per unrolled copy
            const int s = h * 16 + dc;
            const int s2 = (s + 1) & 31;    // wrap keeps issue count uniform (dummy at s=31)

            // ---- issue bundle s+1 (9 DMAs): targets buffers of step s-1 (readers done at barB) ----
            g2l16(xbase + (size_t)(s2 & 15) * 4096 + (wu * 64 + lane) * 16,
                  smem + 65536 + (cb ^ 1) * 4096 + wu * 1024);
            {
                const char* csrc = cbase + (size_t)(s2 >> 4) * 524288 + (size_t)(s2 & 15) * 32768;
                char* cd = smem + (cb ^ 1) * 32768;
#pragma unroll
                for (int i = 0; i < 8; ++i) {
                    int p = i * 4 + wu;
                    g2l16(csrc + p * 1024 + lane * 16, cd + p * 1024);
                }
            }
            __builtin_amdgcn_sched_barrier(0);
            // ---- T4: counted wait — step-s data landed, bundle s+1 (9) stays in flight ----
            asm volatile("s_waitcnt vmcnt(9)" ::: "memory");
            __builtin_amdgcn_s_barrier();   // barA: all waves have step-s data

            // ---- ds_read fragments (asm: no compiler-inserted vmcnt drains) ----
            const unsigned xrd = smemu + 65536u + (unsigned)cb * 4096u + (unsigned)xoff;
            const unsigned brd = smemu + (unsigned)cb * 32768u + (unsigned)(wu * 8192) + (unsigned)xoff;
            half8 a_[4], b_[8];
            a_[0] = ldsr<0>(xrd);    a_[1] = ldsr<1024>(xrd);
            a_[2] = ldsr<2048>(xrd); a_[3] = ldsr<3072>(xrd);
            b_[0] = ldsr<0>(brd);    b_[1] = ldsr<1024>(brd);
            b_[2] = ldsr<2048>(brd); b_[3] = ldsr<3072>(brd);
            b_[4] = ldsr<4096>(brd); b_[5] = ldsr<5120>(brd);
            b_[6] = ldsr<6144>(brd); b_[7] = ldsr<7168>(brd);
            asm volatile("s_waitcnt lgkmcnt(0)" ::: "memory");
            __builtin_amdgcn_sched_barrier(0);  // rule #18: MFMAs must not hoist above the wait

#pragma unroll
            for (int bc = 0; bc < 8; ++bc)
#pragma unroll
                for (int ar = 0; ar < 4; ++ar)
                    acc[ar][bc] = __builtin_amdgcn_mfma_f32_16x16x32_f16(a_[ar], b_[bc], acc[ar][bc], 0, 0, 0);

            __builtin_amdgcn_sched_barrier(0);
            __builtin_amdgcn_s_barrier();   // barB: readers done -> next iter may overwrite s-1 bufs
        }

        // fold this half (ascending cols -> strict < keeps first occurrence)
#pragma unroll
        for (int bc = 0; bc < 8; ++bc) {
            int col = h * 512 + wu * 128 + bc * 16 + ln;
            float cn = (h == 0) ? cnr0[bc] : cnr1[bc];
#pragma unroll
            for (int ar = 0; ar < 4; ++ar)
#pragma unroll
                for (int r = 0; r < 4; ++r) {
                    float sdist = fmaf(-2.f, acc[ar][bc][r], cn);
                    int li = ar * 4 + r;
                    if (sdist < bestS[li]) { bestS[li] = sdist; bestI[li] = col; }
                }
        }
    }

    // butterfly across the 16 ln-lanes (lowest index wins ties)
#pragma unroll
    for (int off = 1; off <= 8; off <<= 1) {
#pragma unroll
        for (int li = 0; li < 16; ++li) {
            float s2 = __shfl_xor(bestS[li], off);
            int i2 = __shfl_xor(bestI[li], off);
            if (s2 < bestS[li] || (s2 == bestS[li] && i2 < bestI[li])) {
                bestS[li] = s2; bestI[li] = i2;
            }
        }
    }
    __syncthreads();  // full drain (incl. wrapped dummy DMAs) before overlay writes
    if (ln == 0) {
#pragma unroll
        for (int li = 0; li < 16; ++li) {
            int row = (li >> 2) * 16 + q * 4 + (li & 3);
            argS[wu * 64 + row] = bestS[li];
            argI[wu * 64 + row] = bestI[li];
        }
    }
    __syncthreads();
    if (t < BM) {  // exactly wave 0
        float s = argS[t];
        int bi = argI[t];
#pragma unroll
        for (int ww = 1; ww < 4; ++ww) {
            float s2 = argS[ww * 64 + t];
            int i2 = argI[ww * 64 + t];
            if (s2 < s || (s2 == s && i2 < bi)) { s = s2; bi = i2; }
        }
        idxF[t] = bi;
        atomicAdd(&hist[bi], 1);
        float l = s + xnorm[rowbase + t];  // ||x - c_best||^2
#pragma unroll
        for (int off = 32; off > 0; off >>= 1) l += __shfl_xor(l, off);
        if (t == 0) atomicAdd(loss_acc, l);
    }
    __syncthreads();
    // gather + write quantized (overwrites this block's own X-fp16 slab only)
    float* outq = (float*)ob + 1;
    for (int m = 0; m < BM; ++m) {
        int bi = idxF[m];
        const float* crow = CB32 + (size_t)bi * DIM;
        float v0 = crow[t];
        float v1 = crow[t + 256];
        size_t base = (size_t)(rowbase + m) * DIM;
        outq[base + t] = v0;
        outq[base + t + 256] = v1;
    }
}

// ---------------- finalize: loss scalar + perplexity ----------------
__global__ __launch_bounds__(256) void finalize_kernel(
    const int* __restrict__ hist, const float* __restrict__ loss_acc,
    float* __restrict__ out, int n_rows, int q_count) {
    __shared__ float wsum[4];
    int t = threadIdx.x;
    float invN = 1.f / (float)n_rows;
    float hsum = 0.f;
    for (int k = t; k < KCB; k += 256) {
        float p = (float)hist[k] * invN;
        hsum += p * logf(p + 1e-10f);
    }
#pragma unroll
    for (int off = 32; off > 0; off >>= 1) hsum += __shfl_xor(hsum, off);
    if ((t & 63) == 0) wsum[t >> 6] = hsum;
    __syncthreads();
    if (t == 0) {
        float H = -(wsum[0] + wsum[1] + wsum[2] + wsum[3]);
        out[0] = loss_acc[0] * (1.25f / (float)q_count);  // q_loss + 0.25*e_loss
        out[1 + q_count] = expf(H);
    }
}

extern "C" void kernel_launch(void* const* d_in, const int* in_sizes, int n_in,
                              void* d_out, int out_size, void* d_ws, size_t ws_size,
                              hipStream_t stream) {
    const float* X = (const float*)d_in[0];
    const float* CB = (const float*)d_in[1];
    char* ob = (char*)d_out;
    char* ws = (char*)d_ws;
    int N = in_sizes[0] / DIM;  // 65536 rows

    hipMemsetAsync(ws + HIST_OFF, 0, 4096 + 64, stream);
    prep<<<2048 + 256, 256, 0, stream>>>(X, CB, ob, ws);

    vq_main<<<N / BM, 256, 73728, stream>>>(ob, CB, ws,
                                            (int*)(ws + HIST_OFF),
                                            (float*)(ws + LOSS_OFF));
    finalize_kernel<<<1, 256, 0, stream>>>((int*)(ws + HIST_OFF),
                                           (float*)(ws + LOSS_OFF),
                                           (float*)d_out, N, N * DIM);
}

// Round 4
// 304.366 us; speedup vs baseline: 1.2340x; 1.2340x over previous
//
#include <hip/hip_runtime.h>
#include <math.h>

#define DIM 512
#define KCB 1024
#define BM  64
// ws layout (bytes)
#define CBT_OFF   0u         // CB fp16 pre-swizzled: [2 halves][16 chunks of 32 d][32KB] = 1 MB
#define CNORM_OFF 1048576u   // 4 KB
#define HIST_OFF  1314816u   // 4 KB
#define LOSS_OFF  1318912u   // 64 B

typedef _Float16 half8 __attribute__((ext_vector_type(8)));
typedef float floatx4 __attribute__((ext_vector_type(4)));

// async global->LDS DMA, 16B/lane; LDS dest = wave-uniform base + lane*16
__device__ __forceinline__ void g2l16(const void* g, void* l) {
    __builtin_amdgcn_global_load_lds(
        (const __attribute__((address_space(1))) unsigned int*)g,
        (__attribute__((address_space(3))) unsigned int*)l, 16, 0, 0);
}

// asm ds_read_b128 with compile-time offset; data valid only after lgkmcnt wait
template<int OFF>
__device__ __forceinline__ half8 ldsr(unsigned addr) {
    half8 r;
    asm volatile("ds_read_b128 %0, %1 offset:%c2" : "=v"(r) : "v"(addr), "n"(OFF));
    return r;
}
// asm ds_write_b128 (addr first); completion tracked via lgkmcnt
__device__ __forceinline__ void ldsw(unsigned addr, half8 v) {
    asm volatile("ds_write_b128 %0, %1" :: "v"(addr), "v"(v) : "memory");
}

__device__ __forceinline__ half8 cvt8(float4 a, float4 b) {
    half8 h;
    h[0] = (_Float16)a.x; h[1] = (_Float16)a.y; h[2] = (_Float16)a.z; h[3] = (_Float16)a.w;
    h[4] = (_Float16)b.x; h[5] = (_Float16)b.y; h[6] = (_Float16)b.z; h[7] = (_Float16)b.w;
    return h;
}
__device__ __forceinline__ float sq8(float4 a, float4 b) {
    return a.x*a.x + a.y*a.y + a.z*a.z + a.w*a.w
         + b.x*b.x + b.y*b.y + b.z*b.z + b.w*b.w;
}

// 32-d chunk image layout: granule = 8 halves (16B) of (row r, q-group q in 0..3).
// line = r>>1 (128B line = 2 rows), slot = ((r&1)*4 + q) ^ (line&7).
// Linear slot order = DMA-compatible (rule #21, pre-swizzled source).

// ---------------- prep: codebook only -> fp16 swizzled chunks + cnorm ----------------
__global__ __launch_bounds__(256) void prep_cb(const float* __restrict__ CB,
                                               char* __restrict__ ws) {
    const int t = threadIdx.x;
    const int w = t >> 6, lane = t & 63;
    const int dc = lane >> 2, q = lane & 3;  // lane covers d = lane*8..+7
    const int k = blockIdx.x * 4 + w;        // one code per wave, k in 0..1023
    const float4* src = (const float4*)(CB + (size_t)k * DIM);
    float4 v0 = src[lane * 2];
    float4 v1 = src[lane * 2 + 1];
    int kl = k & 511;
    int line = kl >> 1;
    int sl = ((((kl & 1) << 2) | q) ^ (line & 7));
    *(half8*)(ws + CBT_OFF + (size_t)(k >> 9) * 524288 + dc * 32768
              + (line * 8 + sl) * 16) = cvt8(v0, v1);
    float s = sq8(v0, v1);
#pragma unroll
    for (int off = 32; off > 0; off >>= 1) s += __shfl_xor(s, off);
    if (lane == 0) ((float*)(ws + CNORM_OFF))[k] = s;
}

// ---------------- main: fused X-staging + counted-vmcnt pipelined MFMA + argmin/epilogue ----------------
__global__ __launch_bounds__(256, 2) void vq_main(
    const float* __restrict__ X, const float* __restrict__ CB32,
    const char* __restrict__ ws, float* __restrict__ outq,
    int* __restrict__ hist, float* __restrict__ loss_acc) {
    extern __shared__ char smem[];
    // cbuf0 @0 (32KB), cbuf1 @32768 (32KB), xbuf0 @65536 (4KB), xbuf1 @69632 (4KB),
    // xnormS @73728 (256B) = 73984 total
    float* argS = (float*)smem;           // epilogue overlay [4][64] (cbuf0 region)
    int*   argI = (int*)(smem + 1024);    // [4][64]
    int*   idxF = (int*)(smem + 2048);    // [64]
    float* xnormS = (float*)(smem + 73728);

    const int t = threadIdx.x;
    const int lane = t & 63;
    const int wu = __builtin_amdgcn_readfirstlane(t >> 6);  // wave id (scalar)
    const int ln = lane & 15, q = lane >> 4;
    const int rb = blockIdx.x;
    const int rowbase = rb * BM;
    const float* cnorm = (const float*)(ws + CNORM_OFF);

    // conflict-free swizzled read offset within a 1KB (16-row) sub-block
    const int xoff = (ln >> 1) * 128 + (((((ln & 1) << 2) | q) ^ (ln >> 1)) << 4);

    const char* cbase = ws + CBT_OFF;
    const unsigned smemu = (unsigned)(uintptr_t)smem;

    // X staging: thread t -> row tr (0..63), q-group tq (0..3); 8 fp32 per step
    const int tr = t >> 2, tq = t & 3;
    const float* xsrc = X + (size_t)(rowbase + tr) * DIM + tq * 8;
    const unsigned xw_off = (unsigned)((((tr >> 1) * 8)
                          + ((((tr & 1) << 2) | tq) ^ ((tr >> 1) & 7))) * 16);

    // preload cnorm into regs (no vector loads left inside the loop)
    float cnr0[8], cnr1[8];
#pragma unroll
    for (int bc = 0; bc < 8; ++bc) {
        cnr0[bc] = cnorm[wu * 128 + bc * 16 + ln];
        cnr1[bc] = cnorm[512 + wu * 128 + bc * 16 + ln];
    }
    asm volatile("" : "+v"(cnr0[0]), "+v"(cnr0[1]), "+v"(cnr0[2]), "+v"(cnr0[3]),
                      "+v"(cnr0[4]), "+v"(cnr0[5]), "+v"(cnr0[6]), "+v"(cnr0[7]));
    asm volatile("" : "+v"(cnr1[0]), "+v"(cnr1[1]), "+v"(cnr1[2]), "+v"(cnr1[3]),
                      "+v"(cnr1[4]), "+v"(cnr1[5]), "+v"(cnr1[6]), "+v"(cnr1[7]));

    float xsq = 0.f;
    float bestS[16];
    int bestI[16];
#pragma unroll
    for (int li = 0; li < 16; ++li) { bestS[li] = 3.0e38f; bestI[li] = 0; }

    // ---- prologue: X(0) via regs + CB(0) via DMA -> buffers 0 ----
    {
        const float4* px = (const float4*)xsrc;      // chunk 0
        float4 p0 = px[0], p1 = px[1];
        __builtin_amdgcn_sched_barrier(0);           // X loads stay oldest
#pragma unroll
        for (int i = 0; i < 8; ++i) {
            int p = i * 4 + wu;
            g2l16(cbase + p * 1024 + lane * 16, smem + p * 1024);
        }
        __builtin_amdgcn_sched_barrier(0);
        xsq += sq8(p0, p1);                          // compiler waits vmcnt(8) here
        ldsw(smemu + 65536u + xw_off, cvt8(p0, p1));
        asm volatile("s_waitcnt vmcnt(0)" ::: "memory");   // CB(0) landed
        asm volatile("s_waitcnt lgkmcnt(0)" ::: "memory"); // X(0) ds_write landed
    }
    __builtin_amdgcn_s_barrier();

    for (int h = 0; h < 2; ++h) {
        floatx4 acc[4][8];
#pragma unroll
        for (int ar = 0; ar < 4; ++ar)
#pragma unroll
            for (int bc = 0; bc < 8; ++bc) acc[ar][bc] = (floatx4){0.f, 0.f, 0.f, 0.f};

#pragma unroll 2
        for (int dc = 0; dc < 16; ++dc) {
            const int cb = dc & 1;          // compile-time per unrolled copy
            const int s = h * 16 + dc;
            const int s2 = (s + 1) & 31;    // wrap keeps issue count uniform (dummy at s=31)

            // ---- A: X(s+1) reg loads (issued FIRST -> oldest of this bundle) ----
            const float4* px = (const float4*)(xsrc + (s2 & 15) * 32);
            float4 p0 = px[0], p1 = px[1];
            __builtin_amdgcn_sched_barrier(0);
            // ---- B: CB(s+1) DMA bundle (8) -> cbuf[cb^1] (readers finished at barB(s-1)) ----
            {
                const char* csrc = cbase + (size_t)(s2 >> 4) * 524288 + (size_t)(s2 & 15) * 32768;
                char* cd = smem + (cb ^ 1) * 32768;
#pragma unroll
                for (int i = 0; i < 8; ++i) {
                    int p = i * 4 + wu;
                    g2l16(csrc + p * 1024 + lane * 16, cd + p * 1024);
                }
            }
            __builtin_amdgcn_sched_barrier(0);
            // ---- C: counted wait — step-s CB DMAs done; 10 of (s+1) stay in flight ----
            asm volatile("s_waitcnt vmcnt(10)" ::: "memory");
            __builtin_amdgcn_s_barrier();   // barA: step-s LDS data ready block-wide

            // ---- E: ds_read fragments ----
            const unsigned xrd = smemu + 65536u + (unsigned)cb * 4096u + (unsigned)xoff;
            const unsigned brd = smemu + (unsigned)cb * 32768u + (unsigned)(wu * 8192) + (unsigned)xoff;
            half8 a_[4], b_[8];
            a_[0] = ldsr<0>(xrd);    a_[1] = ldsr<1024>(xrd);
            a_[2] = ldsr<2048>(xrd); a_[3] = ldsr<3072>(xrd);
            b_[0] = ldsr<0>(brd);    b_[1] = ldsr<1024>(brd);
            b_[2] = ldsr<2048>(brd); b_[3] = ldsr<3072>(brd);
            b_[4] = ldsr<4096>(brd); b_[5] = ldsr<5120>(brd);
            b_[6] = ldsr<6144>(brd); b_[7] = ldsr<7168>(brd);
            asm volatile("s_waitcnt lgkmcnt(0)" ::: "memory");
            __builtin_amdgcn_sched_barrier(0);  // rule #18: MFMAs must not hoist above the wait

            // ---- G: 32 MFMAs ----
#pragma unroll
            for (int bc = 0; bc < 8; ++bc)
#pragma unroll
                for (int ar = 0; ar < 4; ++ar)
                    acc[ar][bc] = __builtin_amdgcn_mfma_f32_16x16x32_f16(a_[ar], b_[bc], acc[ar][bc], 0, 0, 0);

            __builtin_amdgcn_sched_barrier(0);
            // ---- H: write-late X(s+1): waits only own 2 loads (vmcnt(8)), CB DMAs in flight ----
            if (h == 0 && dc < 15) xsq += sq8(p0, p1);
            ldsw(smemu + 65536u + (unsigned)(cb ^ 1) * 4096u + xw_off, cvt8(p0, p1));
            asm volatile("s_waitcnt lgkmcnt(0)" ::: "memory");  // X(s+1) write visible
            __builtin_amdgcn_sched_barrier(0);
            __builtin_amdgcn_s_barrier();   // barB: readers done + X(s+1) in LDS
        }

        if (h == 0) {
            // reduce xsq across the 4 tq-threads of each row (adjacent lanes)
            float xs = xsq;
            xs += __shfl_xor(xs, 1);
            xs += __shfl_xor(xs, 2);
            if ((t & 3) == 0) xnormS[tr] = xs;
        }

        // fold this half (ascending cols -> strict < keeps first occurrence)
#pragma unroll
        for (int bc = 0; bc < 8; ++bc) {
            int col = h * 512 + wu * 128 + bc * 16 + ln;
            float cn = (h == 0) ? cnr0[bc] : cnr1[bc];
#pragma unroll
            for (int ar = 0; ar < 4; ++ar)
#pragma unroll
                for (int r = 0; r < 4; ++r) {
                    float sdist = fmaf(-2.f, acc[ar][bc][r], cn);
                    int li = ar * 4 + r;
                    if (sdist < bestS[li]) { bestS[li] = sdist; bestI[li] = col; }
                }
        }
    }

    // butterfly across the 16 ln-lanes (lowest index wins ties)
#pragma unroll
    for (int off = 1; off <= 8; off <<= 1) {
#pragma unroll
        for (int li = 0; li < 16; ++li) {
            float s2 = __shfl_xor(bestS[li], off);
            int i2 = __shfl_xor(bestI[li], off);
            if (s2 < bestS[li] || (s2 == bestS[li] && i2 < bestI[li])) {
                bestS[li] = s2; bestI[li] = i2;
            }
        }
    }
    __syncthreads();  // full drain (incl. wrapped dummy DMAs) before overlay writes
    if (ln == 0) {
#pragma unroll
        for (int li = 0; li < 16; ++li) {
            int row = (li >> 2) * 16 + q * 4 + (li & 3);
            argS[wu * 64 + row] = bestS[li];
            argI[wu * 64 + row] = bestI[li];
        }
    }
    __syncthreads();
    if (t < BM) {  // exactly wave 0
        float s = argS[t];
        int bi = argI[t];
#pragma unroll
        for (int ww = 1; ww < 4; ++ww) {
            float s2 = argS[ww * 64 + t];
            int i2 = argI[ww * 64 + t];
            if (s2 < s || (s2 == s && i2 < bi)) { s = s2; bi = i2; }
        }
        idxF[t] = bi;
        atomicAdd(&hist[bi], 1);
        float l = s + xnormS[t];  // ||x - c_best||^2
#pragma unroll
        for (int off = 32; off > 0; off >>= 1) l += __shfl_xor(l, off);
        if (t == 0) atomicAdd(loss_acc, l);
    }
    __syncthreads();
    // gather + write quantized (fp32, coalesced)
    for (int m = 0; m < BM; ++m) {
        int bi = idxF[m];
        const float* crow = CB32 + (size_t)bi * DIM;
        float v0 = crow[t];
        float v1 = crow[t + 256];
        size_t base = (size_t)(rowbase + m) * DIM;
        outq[base + t] = v0;
        outq[base + t + 256] = v1;
    }
}

// ---------------- finalize: loss scalar + perplexity ----------------
__global__ __launch_bounds__(256) void finalize_kernel(
    const int* __restrict__ hist, const float* __restrict__ loss_acc,
    float* __restrict__ out, int n_rows, int q_count) {
    __shared__ float wsum[4];
    int t = threadIdx.x;
    float invN = 1.f / (float)n_rows;
    float hsum = 0.f;
    for (int k = t; k < KCB; k += 256) {
        float p = (float)hist[k] * invN;
        hsum += p * logf(p + 1e-10f);
    }
#pragma unroll
    for (int off = 32; off > 0; off >>= 1) hsum += __shfl_xor(hsum, off);
    if ((t & 63) == 0) wsum[t >> 6] = hsum;
    __syncthreads();
    if (t == 0) {
        float H = -(wsum[0] + wsum[1] + wsum[2] + wsum[3]);
        out[0] = loss_acc[0] * (1.25f / (float)q_count);  // q_loss + 0.25*e_loss
        out[1 + q_count] = expf(H);
    }
}

extern "C" void kernel_launch(void* const* d_in, const int* in_sizes, int n_in,
                              void* d_out, int out_size, void* d_ws, size_t ws_size,
                              hipStream_t stream) {
    const float* X = (const float*)d_in[0];
    const float* CB = (const float*)d_in[1];
    char* ws = (char*)d_ws;
    int N = in_sizes[0] / DIM;  // 65536 rows

    hipMemsetAsync(ws + HIST_OFF, 0, 4096 + 64, stream);
    prep_cb<<<256, 256, 0, stream>>>(CB, ws);

    vq_main<<<N / BM, 256, 73984, stream>>>(X, CB, ws,
                                            (float*)d_out + 1,
                                            (int*)(ws + HIST_OFF),
                                            (float*)(ws + LOSS_OFF));
    finalize_kernel<<<1, 256, 0, stream>>>((int*)(ws + HIST_OFF),
                                           (float*)(ws + LOSS_OFF),
                                           (float*)d_out, N, N * DIM);
}